// Round 1
// baseline (7910.554 us; speedup 1.0000x reference)
//
#include <hip/hip_runtime.h>
#include <hip/hip_bf16.h>

// Problem dims
#define T_STEPS 2048
#define BATCH   256
#define INW     64
#define H1      1280
#define H4D     320
#define H8D     160
#define G4      640   // 4*H8
#define ONUM    32

typedef __attribute__((ext_vector_type(8))) short short8;   // 8 x bf16
typedef __attribute__((ext_vector_type(4))) float floatx4;
typedef __hip_bfloat16 bf16;

__device__ __forceinline__ float b2f(bf16 v) { return __bfloat162float(v); }
__device__ __forceinline__ bf16  f2b(float v) { return __float2bfloat16(v); }
__device__ __forceinline__ float fsig(float x)  { return __fdividef(1.0f, 1.0f + __expf(-x)); }
__device__ __forceinline__ float ftanh(float x) { return __fdividef(2.0f, 1.0f + __expf(-2.0f * x)) - 1.0f; }

// ---------------- cast fp32 -> bf16 (vectorized x4) ----------------
struct bf16x4 { bf16 a, b, c, d; };
__global__ void cast_f32_bf16_v4(const float* __restrict__ s, bf16* __restrict__ d, int n4) {
  int i = blockIdx.x * blockDim.x + threadIdx.x;
  if (i >= n4) return;
  float4 v = reinterpret_cast<const float4*>(s)[i];
  bf16x4 o{f2b(v.x), f2b(v.y), f2b(v.z), f2b(v.w)};
  reinterpret_cast<bf16x4*>(d)[i] = o;
}

// ---------------- GEMM: C[M,N] = act(A[M,K] @ W[N,K]^T + bias) ----------------
// 64x64 tile, 256 threads (4 waves, 2x2 wave grid of 32x32), BK=64, bf16 in, bf16 out.
// ACT: 0 = none (no bias), 1 = leaky_relu(0.01) + bias
template <int ACT>
__global__ __launch_bounds__(256) void gemm_bt(
    const bf16* __restrict__ A, const bf16* __restrict__ W,
    const float* __restrict__ bias, bf16* __restrict__ C,
    int M, int N, int K)
{
  __shared__ __align__(16) bf16 As[64][72];   // +8 pad: row stride 144B (16B-aligned, banks spread)
  __shared__ __align__(16) bf16 Ws[64][72];
  const int tid  = threadIdx.x;
  const int lane = tid & 63;
  const int wave = tid >> 6;
  const int mrow = lane & 15;
  const int quad = lane >> 4;
  const int bm = blockIdx.x * 64;
  const int bn = blockIdx.y * 64;
  const int wm = (wave >> 1) * 32;
  const int wn = (wave & 1) * 32;
  const int lr = tid >> 2;  // staging row 0..63
  const int ls = tid & 3;   // staging segment

  floatx4 acc[2][2] = {};

  for (int k0 = 0; k0 < K; k0 += 64) {
    short8 a0 = *reinterpret_cast<const short8*>(&A[(size_t)(bm + lr) * K + k0 + ls * 8]);
    short8 a1 = *reinterpret_cast<const short8*>(&A[(size_t)(bm + lr) * K + k0 + ls * 8 + 32]);
    short8 w0 = *reinterpret_cast<const short8*>(&W[(size_t)(bn + lr) * K + k0 + ls * 8]);
    short8 w1 = *reinterpret_cast<const short8*>(&W[(size_t)(bn + lr) * K + k0 + ls * 8 + 32]);
    __syncthreads();
    *reinterpret_cast<short8*>(&As[lr][ls * 8])      = a0;
    *reinterpret_cast<short8*>(&As[lr][ls * 8 + 32]) = a1;
    *reinterpret_cast<short8*>(&Ws[lr][ls * 8])      = w0;
    *reinterpret_cast<short8*>(&Ws[lr][ls * 8 + 32]) = w1;
    __syncthreads();
#pragma unroll
    for (int kk = 0; kk < 2; ++kk) {
      short8 af0 = *reinterpret_cast<const short8*>(&As[wm + mrow][kk * 32 + quad * 8]);
      short8 af1 = *reinterpret_cast<const short8*>(&As[wm + 16 + mrow][kk * 32 + quad * 8]);
      short8 wf0 = *reinterpret_cast<const short8*>(&Ws[wn + mrow][kk * 32 + quad * 8]);
      short8 wf1 = *reinterpret_cast<const short8*>(&Ws[wn + 16 + mrow][kk * 32 + quad * 8]);
      acc[0][0] = __builtin_amdgcn_mfma_f32_16x16x32_bf16(af0, wf0, acc[0][0], 0, 0, 0);
      acc[0][1] = __builtin_amdgcn_mfma_f32_16x16x32_bf16(af0, wf1, acc[0][1], 0, 0, 0);
      acc[1][0] = __builtin_amdgcn_mfma_f32_16x16x32_bf16(af1, wf0, acc[1][0], 0, 0, 0);
      acc[1][1] = __builtin_amdgcn_mfma_f32_16x16x32_bf16(af1, wf1, acc[1][1], 0, 0, 0);
    }
  }
#pragma unroll
  for (int i = 0; i < 2; ++i) {
#pragma unroll
    for (int j = 0; j < 2; ++j) {
      int col = bn + wn + j * 16 + mrow;
      float bv = (ACT == 1) ? bias[col] : 0.0f;
#pragma unroll
      for (int r = 0; r < 4; ++r) {
        int row = bm + wm + i * 16 + quad * 4 + r;
        float v = acc[i][j][r] + bv;
        if (ACT == 1) v = (v > 0.0f) ? v : 0.01f * v;
        C[(size_t)row * N + col] = f2b(v);
      }
    }
  }
}

// ---------------- recurrent kernel ----------------
// 16 blocks x 512 threads (8 waves). Block b owns batch rows [16b, 16b+16).
// Per step: gates_hh = h @ W_hh^T via MFMA (W_hh fragments resident in VGPRs),
// add gx[t] + biases, LSTM cell elementwise, y = h @ W3^T (waves 0-1).
__global__ __launch_bounds__(512, 2) void recur_kernel(
    const bf16* __restrict__ gx,      // [Tc*256*640]
    const bf16* __restrict__ Whh,     // [640,160] bf16
    const bf16* __restrict__ W3w,     // [32,160]  bf16
    const float* __restrict__ b_ih, const float* __restrict__ b_hh,
    const float* __restrict__ b3,
    bf16* __restrict__ h_ws,          // [256,160] bf16 (persist across chunks)
    float* __restrict__ c_ws,         // [256,160] f32
    float* __restrict__ outp,         // out + chunk offset: [Tc*256*32]
    int Tc, int init)
{
  __shared__ float gates[16][644];               // pad 4: rows 2-way bank alias (free)
  __shared__ __align__(16) bf16 hb[16][168];     // pad 8: 16B-aligned rows, spread banks
  __shared__ float cs[16][160];
  const int tid  = threadIdx.x;
  const int lane = tid & 63;
  const int wave = tid >> 6;    // 0..7 ; wave w owns gate cols [80w, 80w+80)
  const int mrow = lane & 15;
  const int quad = lane >> 4;
  const int bbase = blockIdx.x * 16;

  // W_hh fragments in registers: 5 n-tiles x 5 k-steps = 100 VGPRs/lane
  short8 whf[5][5];
#pragma unroll
  for (int nt = 0; nt < 5; ++nt)
#pragma unroll
    for (int ks = 0; ks < 5; ++ks)
      whf[nt][ks] = *reinterpret_cast<const short8*>(
          &Whh[(size_t)(wave * 80 + nt * 16 + mrow) * 160 + ks * 32 + quad * 8]);

  short8 w3f[5];
  float b3v = 0.0f;
  if (wave < 2) {
#pragma unroll
    for (int ks = 0; ks < 5; ++ks)
      w3f[ks] = *reinterpret_cast<const short8*>(
          &W3w[(size_t)(wave * 16 + mrow) * 160 + ks * 32 + quad * 8]);
    b3v = b3[wave * 16 + mrow];
  }

  // Per-thread bias sums for the 5 cell elements it owns
  float bsum[5][4];
#pragma unroll
  for (int p = 0; p < 5; ++p) {
    int e = tid + p * 512;
    int ix = e % 160;
#pragma unroll
    for (int g = 0; g < 4; ++g)
      bsum[p][g] = b_ih[g * 160 + ix] + b_hh[g * 160 + ix];
  }

  for (int e = tid; e < 16 * 160; e += 512) {
    int r = e / 160, ix = e - r * 160;
    if (init) { hb[r][ix] = f2b(0.0f); cs[r][ix] = 0.0f; }
    else {
      hb[r][ix] = h_ws[(bbase + r) * 160 + ix];
      cs[r][ix] = c_ws[(bbase + r) * 160 + ix];
    }
  }
  __syncthreads();

  for (int t = 0; t < Tc; ++t) {
    // --- hh MFMA: [16,160] @ [160,640] ---
    short8 af[5];
#pragma unroll
    for (int ks = 0; ks < 5; ++ks)
      af[ks] = *reinterpret_cast<const short8*>(&hb[mrow][ks * 32 + quad * 8]);
    floatx4 acc[5] = {};
#pragma unroll
    for (int ks = 0; ks < 5; ++ks)
#pragma unroll
      for (int nt = 0; nt < 5; ++nt)
        acc[nt] = __builtin_amdgcn_mfma_f32_16x16x32_bf16(af[ks], whf[nt][ks], acc[nt], 0, 0, 0);
#pragma unroll
    for (int nt = 0; nt < 5; ++nt)
#pragma unroll
      for (int r = 0; r < 4; ++r)
        gates[quad * 4 + r][wave * 80 + nt * 16 + mrow] = acc[nt][r];
    __syncthreads();

    // --- LSTM cell elementwise: 2560 elems, 5 per thread ---
    const bf16* gxt = gx + ((size_t)t * 256 + bbase) * 640;
#pragma unroll
    for (int p = 0; p < 5; ++p) {
      int e = tid + p * 512;
      int r = e / 160, ix = e - r * 160;
      const bf16* gr = gxt + (size_t)r * 640 + ix;
      float xi = gates[r][ix]       + b2f(gr[0])   + bsum[p][0];
      float xf = gates[r][160 + ix] + b2f(gr[160]) + bsum[p][1];
      float xg = gates[r][320 + ix] + b2f(gr[320]) + bsum[p][2];
      float xo = gates[r][480 + ix] + b2f(gr[480]) + bsum[p][3];
      float iv = fsig(xi), fv = fsig(xf), gv = ftanh(xg), ov = fsig(xo);
      float cv = fv * cs[r][ix] + iv * gv;
      cs[r][ix] = cv;
      hb[r][ix] = f2b(ov * ftanh(cv));
    }
    __syncthreads();

    // --- y = h @ W3^T (waves 0,1), other waves roll into next step ---
    if (wave < 2) {
      short8 hf[5];
#pragma unroll
      for (int ks = 0; ks < 5; ++ks)
        hf[ks] = *reinterpret_cast<const short8*>(&hb[mrow][ks * 32 + quad * 8]);
      floatx4 ya = {};
#pragma unroll
      for (int ks = 0; ks < 5; ++ks)
        ya = __builtin_amdgcn_mfma_f32_16x16x32_bf16(hf[ks], w3f[ks], ya, 0, 0, 0);
      float* op = outp + ((size_t)t * 256 + bbase) * 32 + wave * 16 + mrow;
#pragma unroll
      for (int r = 0; r < 4; ++r)
        op[(size_t)(quad * 4 + r) * 32] = ya[r] + b3v;
    }
  }

  for (int e = tid; e < 16 * 160; e += 512) {
    int r = e / 160, ix = e - r * 160;
    h_ws[(bbase + r) * 160 + ix] = hb[r][ix];
    c_ws[(bbase + r) * 160 + ix] = cs[r][ix];
  }
}

// ---------------- launch ----------------
extern "C" void kernel_launch(void* const* d_in, const int* in_sizes, int n_in,
                              void* d_out, int out_size, void* d_ws, size_t ws_size,
                              hipStream_t stream)
{
  const float* inp = (const float*)d_in[0];
  const float* W1  = (const float*)d_in[1];
  const float* b1  = (const float*)d_in[2];
  const float* W2  = (const float*)d_in[3];
  const float* b2  = (const float*)d_in[4];
  const float* Wih = (const float*)d_in[5];
  const float* Whh = (const float*)d_in[6];
  const float* bih = (const float*)d_in[7];
  const float* bhh = (const float*)d_in[8];
  const float* W3  = (const float*)d_in[9];
  const float* b3  = (const float*)d_in[10];
  float* out = (float*)d_out;

  char* ws = (char*)d_ws;
  size_t off = 0;
  auto alloc = [&](size_t bytes) -> char* {
    char* p = ws + off;
    off += (bytes + 255) & ~(size_t)255;
    return p;
  };

  bf16* inpb = (bf16*)alloc((size_t)T_STEPS * BATCH * INW * 2);
  bf16* w1b  = (bf16*)alloc((size_t)H1 * INW * 2);
  bf16* w2b  = (bf16*)alloc((size_t)H4D * H1 * 2);
  bf16* wihb = (bf16*)alloc((size_t)G4 * H4D * 2);
  bf16* whhb = (bf16*)alloc((size_t)G4 * H8D * 2);
  bf16* w3b  = (bf16*)alloc((size_t)ONUM * H8D * 2);
  bf16* h_ws = (bf16*)alloc((size_t)BATCH * H8D * 2);
  float* c_ws = (float*)alloc((size_t)BATCH * H8D * 4);
  size_t fixed = off;

  int Tc = 128;  // time chunk; shrink if workspace is small
  while (Tc > 16) {
    size_t Mc = (size_t)Tc * BATCH;
    size_t need = fixed
      + ((Mc * H1 * 2 + 255) & ~(size_t)255)
      + ((Mc * H4D * 2 + 255) & ~(size_t)255)
      + ((Mc * G4 * 2 + 255) & ~(size_t)255);
    if (need <= ws_size) break;
    Tc >>= 1;
  }
  const size_t Mc = (size_t)Tc * BATCH;
  bf16* x2 = (bf16*)alloc(Mc * H1 * 2);
  bf16* x4 = (bf16*)alloc(Mc * H4D * 2);
  bf16* gx = (bf16*)alloc(Mc * G4 * 2);

  // casts (done every call; harness re-poisons ws before each timed launch)
  {
    int n4 = T_STEPS * BATCH * INW / 4;
    cast_f32_bf16_v4<<<(n4 + 255) / 256, 256, 0, stream>>>(inp, inpb, n4);
    n4 = H1 * INW / 4;
    cast_f32_bf16_v4<<<(n4 + 255) / 256, 256, 0, stream>>>(W1, w1b, n4);
    n4 = H4D * H1 / 4;
    cast_f32_bf16_v4<<<(n4 + 255) / 256, 256, 0, stream>>>(W2, w2b, n4);
    n4 = G4 * H4D / 4;
    cast_f32_bf16_v4<<<(n4 + 255) / 256, 256, 0, stream>>>(Wih, wihb, n4);
    n4 = G4 * H8D / 4;
    cast_f32_bf16_v4<<<(n4 + 255) / 256, 256, 0, stream>>>(Whh, whhb, n4);
    n4 = ONUM * H8D / 4;
    cast_f32_bf16_v4<<<(n4 + 255) / 256, 256, 0, stream>>>(W3, w3b, n4);
  }

  const int nchunks = T_STEPS / Tc;
  for (int ch = 0; ch < nchunks; ++ch) {
    const bf16* Ain = inpb + (size_t)ch * Mc * INW;
    gemm_bt<1><<<dim3((unsigned)(Mc / 64), H1 / 64), 256, 0, stream>>>(
        Ain, w1b, b1, x2, (int)Mc, H1, INW);
    gemm_bt<1><<<dim3((unsigned)(Mc / 64), H4D / 64), 256, 0, stream>>>(
        x2, w2b, b2, x4, (int)Mc, H4D, H1);
    gemm_bt<0><<<dim3((unsigned)(Mc / 64), G4 / 64), 256, 0, stream>>>(
        x4, wihb, nullptr, gx, (int)Mc, G4, H4D);
    recur_kernel<<<16, 512, 0, stream>>>(
        gx, whhb, w3b, bih, bhh, b3, h_ws, c_ws,
        out + (size_t)ch * Tc * BATCH * ONUM, Tc, ch == 0 ? 1 : 0);
  }
}